// Round 3
// baseline (126.563 us; speedup 1.0000x reference)
//
#include <hip/hip_runtime.h>
#include <math.h>

#define BB 4
#define NN 1024
#define DIN 128
#define DOUT 64
#define SLOPE 0.01f

// Kernel 1: wave-per-row projection. Block = 64 threads = 1 wave, 4096 blocks
// (~16 blocks/CU). Lane l computes x12[row][l] = x[row]@w1[:,l] and
// x12[row][64+l] = x[row]@w2[:,l]. x row broadcast from LDS; w loads are
// coalesced 256B, L1/L2-hot (w1+w2 = 64 KB shared by all blocks).
__global__ __launch_bounds__(64, 4) void proj_kernel(
    const float* __restrict__ x, const float* __restrict__ w1,
    const float* __restrict__ w2, float* __restrict__ x12) {
  int row = blockIdx.x;
  int l = threadIdx.x;
  __shared__ __align__(16) float xl[DIN];
  reinterpret_cast<float2*>(xl)[l] =
      reinterpret_cast<const float2*>(x + (size_t)row * DIN)[l];
  __syncthreads();  // single wave: compiles to waitcnt + cheap barrier
  const float* w1c = w1 + l;
  const float* w2c = w2 + l;
  float a1 = 0.f, a2 = 0.f;
#pragma unroll 8
  for (int k = 0; k < DIN; ++k) {
    float xv = xl[k];  // LDS broadcast
    a1 = fmaf(xv, w1c[k * DOUT], a1);
    a2 = fmaf(xv, w2c[k * DOUT], a2);
  }
  x12[(size_t)row * 128 + l] = a1;
  x12[(size_t)row * 128 + DOUT + l] = a2;
}

__device__ __forceinline__ float fast_edge_exp(float sc) {
  // e = exp(8*tanh(sc/8)); tanh via exp, clamped so __expf stays finite
  float z = sc * 0.125f;
  z = fminf(10.f, fmaxf(-10.f, z));
  float u = __expf(2.f * z);
  float th = (u - 1.f) / (u + 1.f);
  return __expf(8.f * th);
}

// Kernel 2: ONE WAVE per (b,i) row. 64 threads, no multi-wave barriers —
// all phases pipeline within the wave; 4096 blocks give ~16 rows in flight
// per CU to cover HBM/L2 latency.
__global__ __launch_bounds__(64, 4) void gat_row_kernel(
    const float* __restrict__ x, const float* __restrict__ A_shape,
    const float* __restrict__ a_vec, const float* __restrict__ lin_w,
    const float* __restrict__ x12, float* __restrict__ out) {
  int bi = blockIdx.x;  // b*N + i
  int b = bi >> 10;
  int lane = threadIdx.x;

  __shared__ int eidx[NN];                     // 4 KB (worst-case row)
  __shared__ float evals[NN];                  // 4 KB
  __shared__ __align__(16) float x1s[DOUT];    // 256 B
  __shared__ __align__(16) float avs[DOUT];    // 256 B
  __shared__ __align__(16) float agg[DIN];     // 512 B

  // stage x1 row + attention vector (64 floats each, one load per lane)
  x1s[lane] = x12[(size_t)bi * 128 + lane];
  avs[lane] = a_vec[lane];

  // ---- Phase A: load mask row (16 coalesced 256B loads, all independent),
  //      ballot-compact with running scalar base (no atomics) ----
  const float* mask_row = A_shape + (size_t)bi * NN;
  float mv[16];
#pragma unroll
  for (int c = 0; c < 16; ++c) mv[c] = mask_row[c * 64 + lane];
  int base = 0;
#pragma unroll
  for (int c = 0; c < 16; ++c) {
    bool pred = (mv[c] != 0.f);
    unsigned long long m = __ballot(pred);
    int prefix = __popcll(m & ((1ull << lane) - 1ull));
    if (pred) eidx[base + prefix] = c * 64 + lane;
    base += __popcll(m);  // wave-uniform
  }
  int nz = base;
  __syncthreads();  // order LDS writes vs reads (single wave: ~free)

  // ---- Phase B: lane-per-edge scores (nz~51 <= 64: one pass, no reduce) ----
  const float* x2b = x12 + (size_t)b * NN * 128 + DOUT;  // x2 half, stride 128
  float lsum = 0.f;
  for (int s = lane; s < nz; s += 64) {
    const float* x2r = x2b + (size_t)eidx[s] * 128;
    float sc = 0.f;
#pragma unroll
    for (int d0 = 0; d0 < DOUT; d0 += 4) {
      float4 x2v = *reinterpret_cast<const float4*>(x2r + d0);
      float4 x1v = *reinterpret_cast<const float4*>(&x1s[d0]);  // broadcast
      float4 avv = *reinterpret_cast<const float4*>(&avs[d0]);  // broadcast
      float z;
      z = x1v.x + x2v.x; sc = fmaf(z >= 0.f ? z : SLOPE * z, avv.x, sc);
      z = x1v.y + x2v.y; sc = fmaf(z >= 0.f ? z : SLOPE * z, avv.y, sc);
      z = x1v.z + x2v.z; sc = fmaf(z >= 0.f ? z : SLOPE * z, avv.z, sc);
      z = x1v.w + x2v.w; sc = fmaf(z >= 0.f ? z : SLOPE * z, avv.w, sc);
    }
    float e = fast_edge_exp(sc);
    evals[s] = e;
    lsum += e;
  }

  // ---- Phase C: wave-reduce row sum ----
#pragma unroll
  for (int off = 32; off > 0; off >>= 1) lsum += __shfl_xor(lsum, off, 64);
  float inv = 1.f / lsum;
  __syncthreads();

  // ---- Phase D: agg[k] = inv * sum_s evals[s]*x[b,eidx[s],k]
  //      lane owns k=2*lane,2*lane+1: one coalesced 512B load per edge,
  //      fully independent across edges -> deep vmem pipelining ----
  const float* xb = x + (size_t)b * NN * DIN;
  float accx = 0.f, accy = 0.f;
  for (int s = 0; s < nz; ++s) {
    float w = evals[s];          // LDS broadcast
    int j = eidx[s];             // LDS broadcast
    float2 xv = *reinterpret_cast<const float2*>(xb + (size_t)j * 128 + lane * 2);
    accx = fmaf(w, xv.x, accx);
    accy = fmaf(w, xv.y, accy);
  }
  float2 ag2 = {accx * inv, accy * inv};
  reinterpret_cast<float2*>(agg)[lane] = ag2;
  __syncthreads();

  // ---- Phase E: out[d] = lrelu(sum_k agg[k]*lin_w[d,k]), lane = d ----
  const float* lw = lin_w + (size_t)lane * DIN;
  float o = 0.f;
#pragma unroll
  for (int k = 0; k < DIN; k += 4) {
    float4 lv = *reinterpret_cast<const float4*>(lw + k);
    float4 ag = *reinterpret_cast<const float4*>(&agg[k]);  // broadcast
    o = fmaf(ag.x, lv.x, o);
    o = fmaf(ag.y, lv.y, o);
    o = fmaf(ag.z, lv.z, o);
    o = fmaf(ag.w, lv.w, o);
  }
  o = o >= 0.f ? o : SLOPE * o;
  out[(size_t)bi * DOUT + lane] = o;
}

extern "C" void kernel_launch(void* const* d_in, const int* in_sizes, int n_in,
                              void* d_out, int out_size, void* d_ws, size_t ws_size,
                              hipStream_t stream) {
  const float* x = (const float*)d_in[0];
  const float* A_shape = (const float*)d_in[1];
  const float* w1 = (const float*)d_in[2];
  const float* w2 = (const float*)d_in[3];
  const float* a = (const float*)d_in[4];
  const float* lin_w = (const float*)d_in[5];
  float* out = (float*)d_out;
  float* x12 = (float*)d_ws;  // B*N*128 floats = 2 MB scratch

  proj_kernel<<<BB * NN, 64, 0, stream>>>(x, w1, w2, x12);
  gat_row_kernel<<<BB * NN, 64, 0, stream>>>(x, A_shape, a, lin_w, x12, out);
}